// Round 10
// baseline (236.584 us; speedup 1.0000x reference)
//
#include <hip/hip_runtime.h>
#include <hip/hip_bf16.h>
#include <stdint.h>
#include <type_traits>

typedef __attribute__((ext_vector_type(4))) float   f32x4;
typedef __attribute__((ext_vector_type(8))) __bf16  bf16x8;
typedef __attribute__((ext_vector_type(4))) unsigned int u32x4;

#define B_   2
#define S_   2048
#define DIM_ 2048
#define NH_  16
#define NKV_ 8
#define HD_  128

__device__ inline unsigned short f2bf(float f) {
    unsigned u = __float_as_uint(f);
    unsigned r = (u + 0x7fffu + ((u >> 16) & 1u)) >> 16;
    return (unsigned short)r;
}
__device__ inline float bf2f(unsigned short s) {
    return __uint_as_float(((unsigned)s) << 16);
}

// ------- fused fp32 -> bf16 convert (x, wq|wk stacked, wv, wo) + RoPE table -------
__global__ void k_convert(const float* __restrict__ x,  const float* __restrict__ wq,
                          const float* __restrict__ wk, const float* __restrict__ wv,
                          const float* __restrict__ wo,
                          unsigned short* __restrict__ xb,  unsigned short* __restrict__ wqkb,
                          unsigned short* __restrict__ wvb, unsigned short* __restrict__ wob,
                          float* __restrict__ tab)
{
    int i = blockIdx.x * blockDim.x + threadIdx.x;  // quad index
    const int NX = 2097152, NWQ = 1048576, NWK = 524288, NWV = 524288, NWO = 1048576;
    const int NTOT = NX + NWQ + NWK + NWV + NWO;     // 5242880
    if (i >= NTOT) {
        int t = i - NTOT;                            // 0 .. 131071
        if (t >= S_ * 64) return;
        int ii = t & 63;
        int s = t >> 6;
        float inv = expf(-((float)ii / 64.0f) * 9.210340371976184f);  // 10000^(-i/64)
        float ang = (float)s * inv;
        tab[2 * t]     = cosf(ang);
        tab[2 * t + 1] = sinf(ang);
        return;
    }
    const float* src; unsigned short* dst; int j = i;
    if (j < NX) { src = x; dst = xb; }
    else {
        j -= NX;
        if (j < NWQ) { src = wq; dst = wqkb; }
        else {
            j -= NWQ;
            if (j < NWK) { src = wk; dst = wqkb + (size_t)2048 * 2048; }
            else {
                j -= NWK;
                if (j < NWV) { src = wv; dst = wvb; }
                else { j -= NWV; src = wo; dst = wob; }
            }
        }
    }
    float4 v = reinterpret_cast<const float4*>(src)[j];
    ushort4 o;
    o.x = f2bf(v.x); o.y = f2bf(v.y); o.z = f2bf(v.z); o.w = f2bf(v.w);
    reinterpret_cast<ushort4*>(dst)[j] = o;
}

// ================= 256x256 8-phase GEMM (T2+T3+T4+T5), K=2048 =================
#define BAR  __builtin_amdgcn_s_barrier()
#define WLG  asm volatile("s_waitcnt lgkmcnt(0)" ::: "memory")
#define WVM4 asm volatile("s_waitcnt vmcnt(4)" ::: "memory")
#define WVM6 asm volatile("s_waitcnt vmcnt(6)" ::: "memory")
#define WVM0 asm volatile("s_waitcnt vmcnt(0)" ::: "memory")

#define G_LDS(SRC, DST) __builtin_amdgcn_global_load_lds( \
    (const __attribute__((address_space(1))) void*)(SRC), \
    (__attribute__((address_space(3))) void*)(DST), 16, 0, 0)

#define STAGE(MATB, DBUF, HALF, KT) do { \
    const unsigned short* _s0 = ((MATB) ? pb0 : pa0) + (size_t)(HALF) * 128 * 2048 + (KT) * 64; \
    const unsigned short* _s1 = ((MATB) ? pb1 : pa1) + (size_t)(HALF) * 128 * 2048 + (KT) * 64; \
    G_LDS(_s0, lds + (MATB) * 32768 + (DBUF) * 16384 + (HALF) * 8192 + lo0); \
    G_LDS(_s1, lds + (MATB) * 32768 + (DBUF) * 16384 + (HALF) * 8192 + lo1); \
} while (0)

#define LDA(DBUF, MH) { \
    _Pragma("unroll") \
    for (int mf = 0; mf < 4; ++mf) { \
        _Pragma("unroll") \
        for (int kk = 0; kk < 2; ++kk) { \
            const int R = wm * 128 + (MH) * 64 + mf * 16 + lr; \
            afr[MH][mf][kk] = *reinterpret_cast<const bf16x8*>( \
                &lds[(DBUF) * 16384 + R * 64 + (((kk * 4 + g) ^ (lr & 7)) * 8)]); \
        } } }

#define LDB(DBUF, NH) { \
    _Pragma("unroll") \
    for (int nf = 0; nf < 2; ++nf) { \
        _Pragma("unroll") \
        for (int kk = 0; kk < 2; ++kk) { \
            const int R = wn * 64 + (NH) * 32 + nf * 16 + lr; \
            bfr[NH][nf][kk] = *reinterpret_cast<const bf16x8*>( \
                &lds[32768 + (DBUF) * 16384 + R * 64 + (((kk * 4 + g) ^ (lr & 7)) * 8)]); \
        } } }

#define MMA(MH, NH) { \
    __builtin_amdgcn_s_setprio(1); \
    _Pragma("unroll") \
    for (int mf = 0; mf < 4; ++mf) { \
        _Pragma("unroll") \
        for (int nf = 0; nf < 2; ++nf) { \
            _Pragma("unroll") \
            for (int kk = 0; kk < 2; ++kk) \
                acc[(MH) * 4 + mf][(NH) * 2 + nf] = __builtin_amdgcn_mfma_f32_16x16x32_bf16( \
                    afr[MH][mf][kk], bfr[NH][nf][kk], acc[(MH) * 4 + mf][(NH) * 2 + nf], 0, 0, 0); \
        } } \
    __builtin_amdgcn_s_setprio(0); }

// fused QKV (blocks 0..191 QK w/ RoPE epi; 192..255 V^T), grid 256
__global__ __launch_bounds__(512, 2) void k_gemm_qkv(
    const unsigned short* __restrict__ A0g, const unsigned short* __restrict__ B0g,
    const unsigned short* __restrict__ A1g,
    unsigned short* __restrict__ Cq, unsigned short* __restrict__ Cv,
    const float* __restrict__ tab)
{
    __shared__ __attribute__((aligned(16))) unsigned short lds[65536];  // 128 KiB

    const int tid  = threadIdx.x;
    const int lane = tid & 63;
    const int wid  = tid >> 6;
    const int g    = lane >> 4;
    const int lr   = lane & 15;
    const int wm   = wid >> 2;
    const int wn   = wid & 3;

    const unsigned short *Ag, *Bg;
    int brow, bcol;
    bool isQK = true;
    {
        int swz = (blockIdx.x & 7) * 32 + (blockIdx.x >> 3);   // bijective, nwg=256
        if (swz < 192) { Ag = A0g; Bg = B0g; brow = (swz / 12) << 8; bcol = (swz % 12) << 8; }
        else { int ix = swz - 192; isQK = false; Ag = A1g; Bg = A0g; brow = (ix >> 4) << 8; bcol = (ix & 15) << 8; }
    }

    const int E0 = wid * 512 + lane * 8;
    const int E1 = E0 + 4096;
    const int r0 = E0 >> 6, r1 = E1 >> 6;
    const int c0 = ((((E0 >> 3) & 7) ^ (r0 & 7)) * 8);
    const int c1 = ((((E1 >> 3) & 7) ^ (r1 & 7)) * 8);
    const unsigned short* pa0 = Ag + (size_t)(brow + r0) * 2048 + c0;
    const unsigned short* pa1 = Ag + (size_t)(brow + r1) * 2048 + c1;
    const unsigned short* pb0 = Bg + (size_t)(bcol + r0) * 2048 + c0;
    const unsigned short* pb1 = Bg + (size_t)(bcol + r1) * 2048 + c1;
    const int lo0 = wid * 512;
    const int lo1 = lo0 + 4096;

    f32x4 acc[8][4] = {};
    bf16x8 afr[2][4][2];
    bf16x8 bfr[2][2][2];

    STAGE(0, 0, 0, 0); STAGE(0, 0, 1, 0); STAGE(1, 0, 0, 0); STAGE(1, 0, 1, 0);
    STAGE(0, 1, 0, 1); STAGE(1, 1, 0, 1);
    WVM0; BAR;

    #pragma unroll 1
    for (int i = 0; i < 16; ++i) {
        const int kt1 = 2 * i + 1;
        int kt2 = 2 * i + 2;  if (kt2 >= 32) kt2 -= 32;
        int kt3 = 2 * i + 3;  if (kt3 >= 32) kt3 -= 32;
        // P1
        LDA(0, 0); LDB(0, 0);
        STAGE(0, 1, 1, kt1);
        BAR; WLG; MMA(0, 0); BAR;
        // P2
        LDA(0, 1);
        STAGE(1, 1, 1, kt1);
        BAR; WLG; MMA(1, 0); BAR;
        // P3
        LDB(0, 1);
        STAGE(1, 0, 0, kt2);
        BAR; WLG; MMA(0, 1); BAR;
        // P4
        STAGE(0, 0, 0, kt2);
        WVM4;
        BAR; WLG; MMA(1, 1); BAR;
        // P5
        LDA(1, 0); LDB(1, 0);
        STAGE(0, 0, 1, kt2);
        BAR; WLG; MMA(0, 0); BAR;
        // P6
        LDA(1, 1);
        STAGE(1, 0, 1, kt2);
        BAR; WLG; MMA(1, 0); BAR;
        // P7
        LDB(1, 1);
        STAGE(1, 1, 0, kt3);
        BAR; WLG; MMA(0, 1); BAR;
        // P8
        STAGE(0, 1, 0, kt3);
        WVM4;
        BAR; WLG; MMA(1, 1); BAR;
    }

    if (isQK) {
        #pragma unroll
        for (int m = 0; m < 8; ++m) {
            #pragma unroll
            for (int n = 0; n < 4; ++n) {
                int col = bcol + wn * 64 + (n >> 1) * 32 + (n & 1) * 16 + lr;
                int ci  = (col & 127) >> 1;
                int row0 = brow + wm * 128 + (m >> 2) * 64 + (m & 3) * 16 + g * 4;
                #pragma unroll
                for (int r = 0; r < 4; ++r) {
                    int row = row0 + r;
                    int s   = row & (S_ - 1);
                    float2 cs = *reinterpret_cast<const float2*>(&tab[(s * 64 + ci) * 2]);
                    float v = acc[m][n][r];
                    float o = __shfl_xor(v, 1);
                    float res = (lane & 1) ? fmaf(o, cs.y, v * cs.x)
                                           : fmaf(v, cs.x, -(o * cs.y));
                    Cq[(size_t)row * 3072 + col] = f2bf(res);
                }
            }
        }
    } else {
        #pragma unroll
        for (int m = 0; m < 8; ++m)
            #pragma unroll
            for (int n = 0; n < 4; ++n)
                #pragma unroll
                for (int r = 0; r < 4; ++r) {
                    int row = brow + wm * 128 + (m >> 2) * 64 + (m & 3) * 16 + g * 4 + r;
                    int col = bcol + wn * 64 + (n >> 1) * 32 + (n & 1) * 16 + lr;
                    Cv[(size_t)row * 4096 + col] = f2bf(acc[m][n][r]);
                }
    }
}

// ============ out-projection: 128x256 tile, grid 256 (1 block/CU), f32 out ============
#define OP_LDA(D, MH) { \
    _Pragma("unroll") \
    for (int mf = 0; mf < 2; ++mf) { \
        _Pragma("unroll") \
        for (int kk = 0; kk < 2; ++kk) { \
            const int R = wm * 64 + (MH) * 32 + mf * 16 + lr; \
            afr[mf][kk] = *reinterpret_cast<const bf16x8*>( \
                &lds[(D) * 8192 + R * 64 + (((kk * 4 + g) ^ (lr & 7)) * 8)]); \
        } } }

#define OP_LDB(D, NH, BFR) { \
    _Pragma("unroll") \
    for (int nf = 0; nf < 2; ++nf) { \
        _Pragma("unroll") \
        for (int kk = 0; kk < 2; ++kk) { \
            const int R = wn * 64 + (NH) * 32 + nf * 16 + lr; \
            BFR[nf][kk] = *reinterpret_cast<const bf16x8*>( \
                &lds[16384 + (D) * 16384 + R * 64 + (((kk * 4 + g) ^ (lr & 7)) * 8)]); \
        } } }

#define OP_MMA(MH, NH, BFR) { \
    __builtin_amdgcn_s_setprio(1); \
    _Pragma("unroll") \
    for (int mf = 0; mf < 2; ++mf) { \
        _Pragma("unroll") \
        for (int nf = 0; nf < 2; ++nf) { \
            _Pragma("unroll") \
            for (int kk = 0; kk < 2; ++kk) \
                acc[(MH) * 2 + mf][(NH) * 2 + nf] = __builtin_amdgcn_mfma_f32_16x16x32_bf16( \
                    afr[mf][kk], BFR[nf][kk], acc[(MH) * 2 + mf][(NH) * 2 + nf], 0, 0, 0); \
        } } \
    __builtin_amdgcn_s_setprio(0); }

#define OP_SA(D, KT) do { \
    G_LDS(pa0 + (KT) * 64, lds + (D) * 8192 + t8); \
    G_LDS(pa1 + (KT) * 64, lds + (D) * 8192 + 4096 + t8); \
} while (0)
#define OP_SB01(D, KT) do { \
    G_LDS(pb0 + (KT) * 64, lds + 16384 + (D) * 16384 + t8); \
    G_LDS(pb1 + (KT) * 64, lds + 16384 + (D) * 16384 + 4096 + t8); \
} while (0)
#define OP_SB23(D, KT) do { \
    G_LDS(pb2 + (KT) * 64, lds + 16384 + (D) * 16384 + 8192 + t8); \
    G_LDS(pb3 + (KT) * 64, lds + 16384 + (D) * 16384 + 12288 + t8); \
} while (0)

__global__ __launch_bounds__(512, 1) void k_gemm_op(
    const unsigned short* __restrict__ Ag,   // Ob [4096][2048] bf16
    const unsigned short* __restrict__ Bg,   // wob [2048][2048] bf16
    float* __restrict__ C)                   // out [4096][2048] f32
{
    __shared__ __attribute__((aligned(16))) unsigned short lds[49152];  // 96 KiB

    const int tid  = threadIdx.x;
    const int lane = tid & 63;
    const int wid  = tid >> 6;
    const int g    = lane >> 4;
    const int lr   = lane & 15;
    const int wm   = wid >> 2;       // 0,1
    const int wn   = wid & 3;        // 0..3

    const int swz  = (blockIdx.x & 7) * 32 + (blockIdx.x >> 3);  // bijective, nwg=256
    const int brow = (swz >> 3) << 7;    // 32 M-tiles of 128
    const int bcol = (swz & 7) << 8;     // 8 N-tiles of 256

    const int E = tid * 8;
    const int r = E >> 6;
    const int c = (((E >> 3) & 7) ^ (r & 7)) * 8;
    const int t8 = tid * 8;
    const unsigned short* pa0 = Ag + (size_t)(brow + r)       * 2048 + c;
    const unsigned short* pa1 = Ag + (size_t)(brow + 64 + r)  * 2048 + c;
    const unsigned short* pb0 = Bg + (size_t)(bcol + r)       * 2048 + c;
    const unsigned short* pb1 = Bg + (size_t)(bcol + 64 + r)  * 2048 + c;
    const unsigned short* pb2 = Bg + (size_t)(bcol + 128 + r) * 2048 + c;
    const unsigned short* pb3 = Bg + (size_t)(bcol + 192 + r) * 2048 + c;

    f32x4 acc[4][4] = {};
    bf16x8 afr[2][2];
    bf16x8 bfr0[2][2], bfr1[2][2];

    OP_SA(0, 0); OP_SB01(0, 0); OP_SB23(0, 0);
    OP_SA(1, 1); OP_SB01(1, 1); OP_SB23(1, 1);
    WVM0; BAR;

    #pragma unroll 1
    for (int i = 0; i < 16; ++i) {
        int kt2 = 2 * i + 2;  if (kt2 >= 32) kt2 -= 32;
        int kt3 = 2 * i + 3;  if (kt3 >= 32) kt3 -= 32;
        // ---- buf0 (k-tile 2i) ----
        OP_LDA(0, 0); OP_LDB(0, 0, bfr0);
        BAR; WLG; OP_MMA(0, 0, bfr0); BAR;
        OP_LDB(0, 1, bfr1);
        BAR; WLG; OP_MMA(0, 1, bfr1); BAR;
        OP_LDA(0, 1);
        OP_SB01(0, kt2);
        BAR; WLG; OP_MMA(1, 0, bfr0); BAR;
        OP_SB23(0, kt2); OP_SA(0, kt2);
        WVM6;
        BAR; WLG; OP_MMA(1, 1, bfr1); BAR;
        // ---- buf1 (k-tile 2i+1) ----
        OP_LDA(1, 0); OP_LDB(1, 0, bfr0);
        BAR; WLG; OP_MMA(0, 0, bfr0); BAR;
        OP_LDB(1, 1, bfr1);
        BAR; WLG; OP_MMA(0, 1, bfr1); BAR;
        OP_LDA(1, 1);
        OP_SB01(1, kt3);
        BAR; WLG; OP_MMA(1, 0, bfr0); BAR;
        OP_SB23(1, kt3); OP_SA(1, kt3);
        WVM6;
        BAR; WLG; OP_MMA(1, 1, bfr1); BAR;
    }

    #pragma unroll
    for (int m = 0; m < 4; ++m)
        #pragma unroll
        for (int n = 0; n < 4; ++n)
            #pragma unroll
            for (int rr = 0; rr < 4; ++rr) {
                int row = brow + wm * 64 + m * 16 + g * 4 + rr;
                int col = bcol + wn * 64 + n * 16 + lr;
                C[(size_t)row * 2048 + col] = acc[m][n][rr];
            }
}

// ---------------- flash attention (causal, GQA), v7 ----------------
// R8's proven per-tile schedule, re-dimensioned: 256 threads = 4 waves x 16
// q-rows (q-tile 64), grid 1024. LDS 32 KiB -> 5 blocks/CU resident, scheduler
// backfills -> latency hidden by TLP instead of intra-block tricks.
__global__ __launch_bounds__(256, 8) void k_attn(
    const unsigned short* __restrict__ QK,
    const unsigned short* __restrict__ Vt,
    unsigned short* __restrict__ O)
{
    __shared__ __attribute__((aligned(16))) unsigned short Ks[64 * 128];
    __shared__ __attribute__((aligned(16))) unsigned short Vs[128 * 64];

    const int tid  = threadIdx.x;
    const int lane = tid & 63;
    const int wid  = tid >> 6;          // 0..3
    const int g    = lane >> 4;
    const int lr   = lane & 15;

    const int bid    = blockIdx.x;
    const int qt_raw = bid & 31;
    const int h      = (bid >> 5) & 15;
    const int b      = bid >> 9;
    const int qt     = b ? (31 - qt_raw) : qt_raw;   // coarse balance across dispatch order
    const int hk     = h >> 1;
    const int q0w    = qt * 64 + wid * 16;           // 16 q-rows per wave

    bf16x8 qf[4];
    #pragma unroll
    for (int c = 0; c < 4; ++c)
        qf[c] = *reinterpret_cast<const bf16x8*>(
            QK + (size_t)(b * S_ + q0w + lr) * 3072 + h * HD_ + c * 32 + g * 8);

    f32x4 o_acc[8] = {};
    float m_run = -INFINITY;
    float l_run = 0.f;

    const float C2 = 1.4426950408889634f * 0.08838834764831845f;  // log2e/sqrt(128)
    const int nt = qt + 1;
    const int srcb = (g & 1) * 32 + lr;
    const bool hig = g >> 1;

    #pragma unroll 1
    for (int t = 0; t < nt; ++t) {
        const int kv0 = t * 64;
        __syncthreads();   // prev-iter LDS reads complete before DMA overwrite
        // stage K[64][128] + V[128][64], 256 threads, XOR chunk swizzle
        #pragma unroll
        for (int i4 = 0; i4 < 4; ++i4) {
            const int base = (i4 * 4 + wid) * 512;
            const int E = base + lane * 8;
            {   // K tile: row=kv (0..63), 16 chunks/row
                int row = E >> 7, ch = (E >> 3) & 15;
                int col = ((ch ^ (row & 15)) * 8);
                G_LDS(QK + (size_t)(b * S_ + kv0 + row) * 3072 + 2048 + hk * HD_ + col,
                      &Ks[base]);
            }
            {   // V tile: row=d (0..127), 8 chunks/row
                int d = E >> 6, ch = (E >> 3) & 7;
                int kv = ((ch ^ (d & 7)) * 8);
                G_LDS(Vt + (size_t)(hk * HD_ + d) * (B_ * S_) + b * S_ + kv0 + kv,
                      &Vs[base]);
            }
        }
        __syncthreads();

        const bool active = kv0 < q0w + 16;
        if (active) {
            // ---- S^T = K Q^T : sv[kvb][r] = S[kv0+kvb*16+g*4+r][q0w+lr]
            f32x4 sv[4] = {};
            __builtin_amdgcn_s_setprio(1);
            #pragma unroll
            for (int c = 0; c < 4; ++c)
                #pragma unroll
                for (int kvb = 0; kvb < 4; ++kvb) {
                    bf16x8 kf = *reinterpret_cast<const bf16x8*>(
                        &Ks[(kvb * 16 + lr) * 128 + (((c * 4 + g) ^ lr) * 8)]);
                    sv[kvb] = __builtin_amdgcn_mfma_f32_16x16x32_bf16(
                        kf, qf[c], sv[kvb], 0, 0, 0);
                }
            __builtin_amdgcn_s_setprio(0);

            // ---- causal mask (diagonal tiles only): kv > q -> -inf
            if (kv0 + 63 > q0w) {
                int qg = q0w + lr;
                #pragma unroll
                for (int kvb = 0; kvb < 4; ++kvb) {
                    int kvg0 = kv0 + kvb * 16 + g * 4;
                    #pragma unroll
                    for (int r = 0; r < 4; ++r)
                        if (kvg0 + r > qg) sv[kvb][r] = -INFINITY;
                }
            }

            // ---- row max: lane-local + 2 shuffles
            float m0 = fmaxf(fmaxf(fmaxf(sv[0][0], sv[0][1]), fmaxf(sv[0][2], sv[0][3])),
                             fmaxf(fmaxf(sv[1][0], sv[1][1]), fmaxf(sv[1][2], sv[1][3])));
            m0 = fmaxf(m0, fmaxf(fmaxf(sv[2][0], sv[2][1]), fmaxf(sv[2][2], sv[2][3])));
            m0 = fmaxf(m0, fmaxf(fmaxf(sv[3][0], sv[3][1]), fmaxf(sv[3][2], sv[3][3])));
            m0 = fmaxf(m0, __shfl_xor(m0, 16));
            m0 = fmaxf(m0, __shfl_xor(m0, 32));

            // ---- defer-max rescale (THR = 8 scaled = 90.5 raw)
            if (__any(m0 > m_run + 90.5f)) {
                float mn = fmaxf(m_run, m0);
                float al = exp2f((m_run - mn) * C2);
                m_run = mn;
                l_run *= al;
                #pragma unroll
                for (int db = 0; db < 8; ++db)
                    #pragma unroll
                    for (int r = 0; r < 4; ++r)
                        o_acc[db][r] *= al;
            }

            // ---- P = exp2((S-m)*C2); pack bf16 pairs; row sum
            unsigned pk[4][2];
            float mb2 = m_run * C2;
            float rs = 0.f;
            #pragma unroll
            for (int kvb = 0; kvb < 4; ++kvb) {
                float p0 = exp2f(fmaf(sv[kvb][0], C2, -mb2));
                float p1 = exp2f(fmaf(sv[kvb][1], C2, -mb2));
                float p2 = exp2f(fmaf(sv[kvb][2], C2, -mb2));
                float p3 = exp2f(fmaf(sv[kvb][3], C2, -mb2));
                rs += (p0 + p1) + (p2 + p3);
                pk[kvb][0] = (unsigned)f2bf(p0) | ((unsigned)f2bf(p1) << 16);
                pk[kvb][1] = (unsigned)f2bf(p2) | ((unsigned)f2bf(p3) << 16);
            }
            rs += __shfl_xor(rs, 16);
            rs += __shfl_xor(rs, 32);
            l_run += rs;

            // ---- in-register transpose to PV B-frag + O^T += V^T P^T
            #pragma unroll
            for (int kk = 0; kk < 2; ++kk) {
                u32x4 w;
                unsigned a0 = (unsigned)__shfl((int)pk[2 * kk][0], srcb);
                unsigned a1 = (unsigned)__shfl((int)pk[2 * kk][1], srcb);
                unsigned a2 = (unsigned)__shfl((int)pk[2 * kk][0], srcb + 16);
                unsigned a3 = (unsigned)__shfl((int)pk[2 * kk][1], srcb + 16);
                unsigned b0 = (unsigned)__shfl((int)pk[2 * kk + 1][0], srcb);
                unsigned b1 = (unsigned)__shfl((int)pk[2 * kk + 1][1], srcb);
                unsigned b2 = (unsigned)__shfl((int)pk[2 * kk + 1][0], srcb + 16);
                unsigned b3 = (unsigned)__shfl((int)pk[2 * kk + 1][1], srcb + 16);
                w[0] = hig ? b0 : a0;
                w[1] = hig ? b1 : a1;
                w[2] = hig ? b2 : a2;
                w[3] = hig ? b3 : a3;
                bf16x8 pb = *reinterpret_cast<const bf16x8*>(&w);
                __builtin_amdgcn_s_setprio(1);
                #pragma unroll
                for (int db = 0; db < 8; ++db) {
                    bf16x8 vf = *reinterpret_cast<const bf16x8*>(
                        &Vs[(db * 16 + lr) * 64 + (((kk * 4 + g) ^ (lr & 7)) * 8)]);
                    o_acc[db] = __builtin_amdgcn_mfma_f32_16x16x32_bf16(
                        vf, pb, o_acc[db], 0, 0, 0);
                }
                __builtin_amdgcn_s_setprio(0);
            }
        }
    }

    // ---- epilogue: normalize, store bf16 [b,s,h,d]; 8B stores
    {
        float inv = 1.f / l_run;
        size_t rowb = ((size_t)(b * S_ + q0w + lr) * NH_ + h) * HD_;
        #pragma unroll
        for (int db = 0; db < 8; ++db) {
            ushort4 o4;
            o4.x = f2bf(o_acc[db][0] * inv);
            o4.y = f2bf(o_acc[db][1] * inv);
            o4.z = f2bf(o_acc[db][2] * inv);
            o4.w = f2bf(o_acc[db][3] * inv);
            *reinterpret_cast<ushort4*>(&O[rowb + db * 16 + g * 4]) = o4;
        }
    }
}

// ---------------- launcher ----------------
extern "C" void kernel_launch(void* const* d_in, const int* in_sizes, int n_in,
                              void* d_out, int out_size, void* d_ws, size_t ws_size,
                              hipStream_t stream)
{
    const float* x  = (const float*)d_in[0];
    const float* wq = (const float*)d_in[1];
    const float* wk = (const float*)d_in[2];
    const float* wv = (const float*)d_in[3];
    const float* wo = (const float*)d_in[4];
    float* out = (float*)d_out;

    char* ws = (char*)d_ws;
    size_t off = 0;
    auto alloc = [&](size_t bytes) -> void* {
        void* p = ws + off;
        off += (bytes + 255) & ~(size_t)255;
        return p;
    };
    unsigned short* xb   = (unsigned short*)alloc((size_t)B_ * S_ * DIM_ * 2);
    unsigned short* wqkb = (unsigned short*)alloc((size_t)3072 * 2048 * 2);
    unsigned short* wvb  = (unsigned short*)alloc((size_t)1024 * 2048 * 2);
    unsigned short* wob  = (unsigned short*)alloc((size_t)DIM_ * DIM_ * 2);
    unsigned short* QKb  = (unsigned short*)alloc((size_t)B_ * S_ * 3072 * 2);
    unsigned short* Vtb  = (unsigned short*)alloc((size_t)1024 * B_ * S_ * 2);
    unsigned short* Ob   = (unsigned short*)alloc((size_t)B_ * S_ * NH_ * HD_ * 2);
    float* tab = (float*)alloc((size_t)S_ * 64 * 2 * 4);

    k_convert<<<20992, 256, 0, stream>>>(x, wq, wk, wv, wo, xb, wqkb, wvb, wob, tab);
    k_gemm_qkv<<<256, 512, 0, stream>>>(xb, wqkb, wvb, QKb, Vtb, tab);
    k_attn<<<B_ * NH_ * (S_ / 64), 256, 0, stream>>>(QKb, Vtb, Ob);
    k_gemm_op<<<256, 512, 0, stream>>>(Ob, wob, out);

    (void)in_sizes; (void)n_in; (void)out_size; (void)ws_size;
}

// Round 11
// 208.264 us; speedup vs baseline: 1.1360x; 1.1360x over previous
//
#include <hip/hip_runtime.h>
#include <hip/hip_bf16.h>
#include <stdint.h>
#include <type_traits>

typedef __attribute__((ext_vector_type(4))) float   f32x4;
typedef __attribute__((ext_vector_type(8))) __bf16  bf16x8;
typedef __attribute__((ext_vector_type(4))) unsigned int u32x4;

#define B_   2
#define S_   2048
#define DIM_ 2048
#define NH_  16
#define NKV_ 8
#define HD_  128

__device__ inline unsigned short f2bf(float f) {
    unsigned u = __float_as_uint(f);
    unsigned r = (u + 0x7fffu + ((u >> 16) & 1u)) >> 16;
    return (unsigned short)r;
}
__device__ inline float bf2f(unsigned short s) {
    return __uint_as_float(((unsigned)s) << 16);
}

// ------- fused fp32 -> bf16 convert (x, wq|wk stacked, wv, wo) + RoPE table -------
__global__ void k_convert(const float* __restrict__ x,  const float* __restrict__ wq,
                          const float* __restrict__ wk, const float* __restrict__ wv,
                          const float* __restrict__ wo,
                          unsigned short* __restrict__ xb,  unsigned short* __restrict__ wqkb,
                          unsigned short* __restrict__ wvb, unsigned short* __restrict__ wob,
                          float* __restrict__ tab)
{
    int i = blockIdx.x * blockDim.x + threadIdx.x;  // quad index
    const int NX = 2097152, NWQ = 1048576, NWK = 524288, NWV = 524288, NWO = 1048576;
    const int NTOT = NX + NWQ + NWK + NWV + NWO;     // 5242880
    if (i >= NTOT) {
        int t = i - NTOT;                            // 0 .. 131071
        if (t >= S_ * 64) return;
        int ii = t & 63;
        int s = t >> 6;
        float inv = expf(-((float)ii / 64.0f) * 9.210340371976184f);  // 10000^(-i/64)
        float ang = (float)s * inv;
        tab[2 * t]     = cosf(ang);
        tab[2 * t + 1] = sinf(ang);
        return;
    }
    const float* src; unsigned short* dst; int j = i;
    if (j < NX) { src = x; dst = xb; }
    else {
        j -= NX;
        if (j < NWQ) { src = wq; dst = wqkb; }
        else {
            j -= NWQ;
            if (j < NWK) { src = wk; dst = wqkb + (size_t)2048 * 2048; }
            else {
                j -= NWK;
                if (j < NWV) { src = wv; dst = wvb; }
                else { j -= NWV; src = wo; dst = wob; }
            }
        }
    }
    float4 v = reinterpret_cast<const float4*>(src)[j];
    ushort4 o;
    o.x = f2bf(v.x); o.y = f2bf(v.y); o.z = f2bf(v.z); o.w = f2bf(v.w);
    reinterpret_cast<ushort4*>(dst)[j] = o;
}

// ================= 256x256 8-phase GEMM (T2+T3+T4+T5), K=2048 =================
#define BAR  __builtin_amdgcn_s_barrier()
#define WLG  asm volatile("s_waitcnt lgkmcnt(0)" ::: "memory")
#define WVM4 asm volatile("s_waitcnt vmcnt(4)" ::: "memory")
#define WVM6 asm volatile("s_waitcnt vmcnt(6)" ::: "memory")
#define WVM0 asm volatile("s_waitcnt vmcnt(0)" ::: "memory")

#define G_LDS(SRC, DST) __builtin_amdgcn_global_load_lds( \
    (const __attribute__((address_space(1))) void*)(SRC), \
    (__attribute__((address_space(3))) void*)(DST), 16, 0, 0)

#define STAGE(MATB, DBUF, HALF, KT) do { \
    const unsigned short* _s0 = ((MATB) ? pb0 : pa0) + (size_t)(HALF) * 128 * 2048 + (KT) * 64; \
    const unsigned short* _s1 = ((MATB) ? pb1 : pa1) + (size_t)(HALF) * 128 * 2048 + (KT) * 64; \
    G_LDS(_s0, lds + (MATB) * 32768 + (DBUF) * 16384 + (HALF) * 8192 + lo0); \
    G_LDS(_s1, lds + (MATB) * 32768 + (DBUF) * 16384 + (HALF) * 8192 + lo1); \
} while (0)

#define LDA(DBUF, MH) { \
    _Pragma("unroll") \
    for (int mf = 0; mf < 4; ++mf) { \
        _Pragma("unroll") \
        for (int kk = 0; kk < 2; ++kk) { \
            const int R = wm * 128 + (MH) * 64 + mf * 16 + lr; \
            afr[MH][mf][kk] = *reinterpret_cast<const bf16x8*>( \
                &lds[(DBUF) * 16384 + R * 64 + (((kk * 4 + g) ^ (lr & 7)) * 8)]); \
        } } }

#define LDB(DBUF, NH) { \
    _Pragma("unroll") \
    for (int nf = 0; nf < 2; ++nf) { \
        _Pragma("unroll") \
        for (int kk = 0; kk < 2; ++kk) { \
            const int R = wn * 64 + (NH) * 32 + nf * 16 + lr; \
            bfr[NH][nf][kk] = *reinterpret_cast<const bf16x8*>( \
                &lds[32768 + (DBUF) * 16384 + R * 64 + (((kk * 4 + g) ^ (lr & 7)) * 8)]); \
        } } }

#define MMA(MH, NH) { \
    __builtin_amdgcn_s_setprio(1); \
    _Pragma("unroll") \
    for (int mf = 0; mf < 4; ++mf) { \
        _Pragma("unroll") \
        for (int nf = 0; nf < 2; ++nf) { \
            _Pragma("unroll") \
            for (int kk = 0; kk < 2; ++kk) \
                acc[(MH) * 4 + mf][(NH) * 2 + nf] = __builtin_amdgcn_mfma_f32_16x16x32_bf16( \
                    afr[MH][mf][kk], bfr[NH][nf][kk], acc[(MH) * 4 + mf][(NH) * 2 + nf], 0, 0, 0); \
        } } \
    __builtin_amdgcn_s_setprio(0); }

// fused QKV (blocks 0..191 QK w/ RoPE epi; 192..255 V^T), grid 256
__global__ __launch_bounds__(512, 2) void k_gemm_qkv(
    const unsigned short* __restrict__ A0g, const unsigned short* __restrict__ B0g,
    const unsigned short* __restrict__ A1g,
    unsigned short* __restrict__ Cq, unsigned short* __restrict__ Cv,
    const float* __restrict__ tab)
{
    __shared__ __attribute__((aligned(16))) unsigned short lds[65536];  // 128 KiB

    const int tid  = threadIdx.x;
    const int lane = tid & 63;
    const int wid  = tid >> 6;
    const int g    = lane >> 4;
    const int lr   = lane & 15;
    const int wm   = wid >> 2;
    const int wn   = wid & 3;

    const unsigned short *Ag, *Bg;
    int brow, bcol;
    bool isQK = true;
    {
        int swz = (blockIdx.x & 7) * 32 + (blockIdx.x >> 3);   // bijective, nwg=256
        if (swz < 192) { Ag = A0g; Bg = B0g; brow = (swz / 12) << 8; bcol = (swz % 12) << 8; }
        else { int ix = swz - 192; isQK = false; Ag = A1g; Bg = A0g; brow = (ix >> 4) << 8; bcol = (ix & 15) << 8; }
    }

    const int E0 = wid * 512 + lane * 8;
    const int E1 = E0 + 4096;
    const int r0 = E0 >> 6, r1 = E1 >> 6;
    const int c0 = ((((E0 >> 3) & 7) ^ (r0 & 7)) * 8);
    const int c1 = ((((E1 >> 3) & 7) ^ (r1 & 7)) * 8);
    const unsigned short* pa0 = Ag + (size_t)(brow + r0) * 2048 + c0;
    const unsigned short* pa1 = Ag + (size_t)(brow + r1) * 2048 + c1;
    const unsigned short* pb0 = Bg + (size_t)(bcol + r0) * 2048 + c0;
    const unsigned short* pb1 = Bg + (size_t)(bcol + r1) * 2048 + c1;
    const int lo0 = wid * 512;
    const int lo1 = lo0 + 4096;

    f32x4 acc[8][4] = {};
    bf16x8 afr[2][4][2];
    bf16x8 bfr[2][2][2];

    STAGE(0, 0, 0, 0); STAGE(0, 0, 1, 0); STAGE(1, 0, 0, 0); STAGE(1, 0, 1, 0);
    STAGE(0, 1, 0, 1); STAGE(1, 1, 0, 1);
    WVM0; BAR;

    #pragma unroll 1
    for (int i = 0; i < 16; ++i) {
        const int kt1 = 2 * i + 1;
        int kt2 = 2 * i + 2;  if (kt2 >= 32) kt2 -= 32;
        int kt3 = 2 * i + 3;  if (kt3 >= 32) kt3 -= 32;
        // P1
        LDA(0, 0); LDB(0, 0);
        STAGE(0, 1, 1, kt1);
        BAR; WLG; MMA(0, 0); BAR;
        // P2
        LDA(0, 1);
        STAGE(1, 1, 1, kt1);
        BAR; WLG; MMA(1, 0); BAR;
        // P3
        LDB(0, 1);
        STAGE(1, 0, 0, kt2);
        BAR; WLG; MMA(0, 1); BAR;
        // P4
        STAGE(0, 0, 0, kt2);
        WVM4;
        BAR; WLG; MMA(1, 1); BAR;
        // P5
        LDA(1, 0); LDB(1, 0);
        STAGE(0, 0, 1, kt2);
        BAR; WLG; MMA(0, 0); BAR;
        // P6
        LDA(1, 1);
        STAGE(1, 0, 1, kt2);
        BAR; WLG; MMA(1, 0); BAR;
        // P7
        LDB(1, 1);
        STAGE(1, 1, 0, kt3);
        BAR; WLG; MMA(0, 1); BAR;
        // P8
        STAGE(0, 1, 0, kt3);
        WVM4;
        BAR; WLG; MMA(1, 1); BAR;
    }

    if (isQK) {
        #pragma unroll
        for (int m = 0; m < 8; ++m) {
            #pragma unroll
            for (int n = 0; n < 4; ++n) {
                int col = bcol + wn * 64 + (n >> 1) * 32 + (n & 1) * 16 + lr;
                int ci  = (col & 127) >> 1;
                int row0 = brow + wm * 128 + (m >> 2) * 64 + (m & 3) * 16 + g * 4;
                #pragma unroll
                for (int r = 0; r < 4; ++r) {
                    int row = row0 + r;
                    int s   = row & (S_ - 1);
                    float2 cs = *reinterpret_cast<const float2*>(&tab[(s * 64 + ci) * 2]);
                    float v = acc[m][n][r];
                    float o = __shfl_xor(v, 1);
                    float res = (lane & 1) ? fmaf(o, cs.y, v * cs.x)
                                           : fmaf(v, cs.x, -(o * cs.y));
                    Cq[(size_t)row * 3072 + col] = f2bf(res);
                }
            }
        }
    } else {
        #pragma unroll
        for (int m = 0; m < 8; ++m)
            #pragma unroll
            for (int n = 0; n < 4; ++n)
                #pragma unroll
                for (int r = 0; r < 4; ++r) {
                    int row = brow + wm * 128 + (m >> 2) * 64 + (m & 3) * 16 + g * 4 + r;
                    int col = bcol + wn * 64 + (n >> 1) * 32 + (n & 1) * 16 + lr;
                    Cv[(size_t)row * 4096 + col] = f2bf(acc[m][n][r]);
                }
    }
}

// ============ out-projection: 128x256 tile, grid 256 (1 block/CU), f32 out ============
#define OP_LDA(D, MH) { \
    _Pragma("unroll") \
    for (int mf = 0; mf < 2; ++mf) { \
        _Pragma("unroll") \
        for (int kk = 0; kk < 2; ++kk) { \
            const int R = wm * 64 + (MH) * 32 + mf * 16 + lr; \
            afr[mf][kk] = *reinterpret_cast<const bf16x8*>( \
                &lds[(D) * 8192 + R * 64 + (((kk * 4 + g) ^ (lr & 7)) * 8)]); \
        } } }

#define OP_LDB(D, NH, BFR) { \
    _Pragma("unroll") \
    for (int nf = 0; nf < 2; ++nf) { \
        _Pragma("unroll") \
        for (int kk = 0; kk < 2; ++kk) { \
            const int R = wn * 64 + (NH) * 32 + nf * 16 + lr; \
            BFR[nf][kk] = *reinterpret_cast<const bf16x8*>( \
                &lds[16384 + (D) * 16384 + R * 64 + (((kk * 4 + g) ^ (lr & 7)) * 8)]); \
        } } }

#define OP_MMA(MH, NH, BFR) { \
    __builtin_amdgcn_s_setprio(1); \
    _Pragma("unroll") \
    for (int mf = 0; mf < 2; ++mf) { \
        _Pragma("unroll") \
        for (int nf = 0; nf < 2; ++nf) { \
            _Pragma("unroll") \
            for (int kk = 0; kk < 2; ++kk) \
                acc[(MH) * 2 + mf][(NH) * 2 + nf] = __builtin_amdgcn_mfma_f32_16x16x32_bf16( \
                    afr[mf][kk], BFR[nf][kk], acc[(MH) * 2 + mf][(NH) * 2 + nf], 0, 0, 0); \
        } } \
    __builtin_amdgcn_s_setprio(0); }

#define OP_SA(D, KT) do { \
    G_LDS(pa0 + (KT) * 64, lds + (D) * 8192 + t8); \
    G_LDS(pa1 + (KT) * 64, lds + (D) * 8192 + 4096 + t8); \
} while (0)
#define OP_SB01(D, KT) do { \
    G_LDS(pb0 + (KT) * 64, lds + 16384 + (D) * 16384 + t8); \
    G_LDS(pb1 + (KT) * 64, lds + 16384 + (D) * 16384 + 4096 + t8); \
} while (0)
#define OP_SB23(D, KT) do { \
    G_LDS(pb2 + (KT) * 64, lds + 16384 + (D) * 16384 + 8192 + t8); \
    G_LDS(pb3 + (KT) * 64, lds + 16384 + (D) * 16384 + 12288 + t8); \
} while (0)

__global__ __launch_bounds__(512, 1) void k_gemm_op(
    const unsigned short* __restrict__ Ag,   // Ob [4096][2048] bf16
    const unsigned short* __restrict__ Bg,   // wob [2048][2048] bf16
    float* __restrict__ C)                   // out [4096][2048] f32
{
    __shared__ __attribute__((aligned(16))) unsigned short lds[49152];  // 96 KiB

    const int tid  = threadIdx.x;
    const int lane = tid & 63;
    const int wid  = tid >> 6;
    const int g    = lane >> 4;
    const int lr   = lane & 15;
    const int wm   = wid >> 2;       // 0,1
    const int wn   = wid & 3;        // 0..3

    const int swz  = (blockIdx.x & 7) * 32 + (blockIdx.x >> 3);  // bijective, nwg=256
    const int brow = (swz >> 3) << 7;    // 32 M-tiles of 128
    const int bcol = (swz & 7) << 8;     // 8 N-tiles of 256

    const int E = tid * 8;
    const int r = E >> 6;
    const int c = (((E >> 3) & 7) ^ (r & 7)) * 8;
    const int t8 = tid * 8;
    const unsigned short* pa0 = Ag + (size_t)(brow + r)       * 2048 + c;
    const unsigned short* pa1 = Ag + (size_t)(brow + 64 + r)  * 2048 + c;
    const unsigned short* pb0 = Bg + (size_t)(bcol + r)       * 2048 + c;
    const unsigned short* pb1 = Bg + (size_t)(bcol + 64 + r)  * 2048 + c;
    const unsigned short* pb2 = Bg + (size_t)(bcol + 128 + r) * 2048 + c;
    const unsigned short* pb3 = Bg + (size_t)(bcol + 192 + r) * 2048 + c;

    f32x4 acc[4][4] = {};
    bf16x8 afr[2][2];
    bf16x8 bfr0[2][2], bfr1[2][2];

    OP_SA(0, 0); OP_SB01(0, 0); OP_SB23(0, 0);
    OP_SA(1, 1); OP_SB01(1, 1); OP_SB23(1, 1);
    WVM0; BAR;

    #pragma unroll 1
    for (int i = 0; i < 16; ++i) {
        int kt2 = 2 * i + 2;  if (kt2 >= 32) kt2 -= 32;
        int kt3 = 2 * i + 3;  if (kt3 >= 32) kt3 -= 32;
        // ---- buf0 (k-tile 2i) ----
        OP_LDA(0, 0); OP_LDB(0, 0, bfr0);
        BAR; WLG; OP_MMA(0, 0, bfr0); BAR;
        OP_LDB(0, 1, bfr1);
        BAR; WLG; OP_MMA(0, 1, bfr1); BAR;
        OP_LDA(0, 1);
        OP_SB01(0, kt2);
        BAR; WLG; OP_MMA(1, 0, bfr0); BAR;
        OP_SB23(0, kt2); OP_SA(0, kt2);
        WVM6;
        BAR; WLG; OP_MMA(1, 1, bfr1); BAR;
        // ---- buf1 (k-tile 2i+1) ----
        OP_LDA(1, 0); OP_LDB(1, 0, bfr0);
        BAR; WLG; OP_MMA(0, 0, bfr0); BAR;
        OP_LDB(1, 1, bfr1);
        BAR; WLG; OP_MMA(0, 1, bfr1); BAR;
        OP_LDA(1, 1);
        OP_SB01(1, kt3);
        BAR; WLG; OP_MMA(1, 0, bfr0); BAR;
        OP_SB23(1, kt3); OP_SA(1, kt3);
        WVM6;
        BAR; WLG; OP_MMA(1, 1, bfr1); BAR;
    }

    #pragma unroll
    for (int m = 0; m < 4; ++m)
        #pragma unroll
        for (int n = 0; n < 4; ++n)
            #pragma unroll
            for (int rr = 0; rr < 4; ++rr) {
                int row = brow + wm * 64 + m * 16 + g * 4 + rr;
                int col = bcol + wn * 64 + n * 16 + lr;
                C[(size_t)row * 2048 + col] = acc[m][n][rr];
            }
}

// ---------------- flash attention (causal, GQA), v8 ----------------
// R8's proven 512-thr kernel; ONLY the block decode changed: bid&7 = hk so all
// 64 blocks reading one hk's K/V land on one XCD (round-robin dispatch) -> K/V
// re-reads (2 MB/XCD working set) hit the XCD-local 4 MB L2 instead of L3.
// bit8 = b preserves the bid/bid+256 co-resident (qt, 15-qt) 34-tile balance.
__global__ __launch_bounds__(512, 4) void k_attn(
    const unsigned short* __restrict__ QK,
    const unsigned short* __restrict__ Vt,
    unsigned short* __restrict__ O)
{
    __shared__ __attribute__((aligned(16))) unsigned short Ks[64 * 128];
    __shared__ __attribute__((aligned(16))) unsigned short Vs[128 * 64];

    const int tid  = threadIdx.x;
    const int lane = tid & 63;
    const int wid  = tid >> 6;          // 0..7
    const int g    = lane >> 4;
    const int lr   = lane & 15;

    const int bid    = blockIdx.x;
    const int hk     = bid & 7;                      // XCD-local K/V slab
    const int h      = (hk << 1) | ((bid >> 3) & 1);
    const int qt_raw = (bid >> 4) & 15;
    const int b      = bid >> 8;
    const int qt     = b ? (15 - qt_raw) : qt_raw;   // co-resident pair balance
    const int q0w    = qt * 128 + wid * 16;          // 16 q-rows per wave

    bf16x8 qf[4];
    #pragma unroll
    for (int c = 0; c < 4; ++c)
        qf[c] = *reinterpret_cast<const bf16x8*>(
            QK + (size_t)(b * S_ + q0w + lr) * 3072 + h * HD_ + c * 32 + g * 8);

    f32x4 o_acc[8] = {};
    float m_run = -INFINITY;
    float l_run = 0.f;

    const float C2 = 1.4426950408889634f * 0.08838834764831845f;  // log2e/sqrt(128)
    const int nt = 2 * qt + 2;
    const int srcb = (g & 1) * 32 + lr;
    const bool hig = g >> 1;

    #pragma unroll 1
    for (int t = 0; t < nt; ++t) {
        const int kv0 = t * 64;
        __syncthreads();   // prev-iter LDS reads complete before DMA overwrite
        #pragma unroll
        for (int i4 = 0; i4 < 2; ++i4) {
            const int base = (i4 * 8 + wid) * 512;
            const int E = base + lane * 8;
            {   // K tile: row=kv (0..63), 16 chunks/row
                int row = E >> 7, ch = (E >> 3) & 15;
                int col = ((ch ^ (row & 15)) * 8);
                G_LDS(QK + (size_t)(b * S_ + kv0 + row) * 3072 + 2048 + hk * HD_ + col,
                      &Ks[base]);
            }
            {   // V tile: row=d (0..127), 8 chunks/row
                int d = E >> 6, ch = (E >> 3) & 7;
                int kv = ((ch ^ (d & 7)) * 8);
                G_LDS(Vt + (size_t)(hk * HD_ + d) * (B_ * S_) + b * S_ + kv0 + kv,
                      &Vs[base]);
            }
        }
        __syncthreads();

        const bool active = kv0 < q0w + 16;
        if (active) {
            f32x4 sv[4] = {};
            __builtin_amdgcn_s_setprio(1);
            #pragma unroll
            for (int c = 0; c < 4; ++c)
                #pragma unroll
                for (int kvb = 0; kvb < 4; ++kvb) {
                    bf16x8 kf = *reinterpret_cast<const bf16x8*>(
                        &Ks[(kvb * 16 + lr) * 128 + (((c * 4 + g) ^ lr) * 8)]);
                    sv[kvb] = __builtin_amdgcn_mfma_f32_16x16x32_bf16(
                        kf, qf[c], sv[kvb], 0, 0, 0);
                }
            __builtin_amdgcn_s_setprio(0);

            if (kv0 + 63 > q0w) {
                int qg = q0w + lr;
                #pragma unroll
                for (int kvb = 0; kvb < 4; ++kvb) {
                    int kvg0 = kv0 + kvb * 16 + g * 4;
                    #pragma unroll
                    for (int r = 0; r < 4; ++r)
                        if (kvg0 + r > qg) sv[kvb][r] = -INFINITY;
                }
            }

            float m0 = fmaxf(fmaxf(fmaxf(sv[0][0], sv[0][1]), fmaxf(sv[0][2], sv[0][3])),
                             fmaxf(fmaxf(sv[1][0], sv[1][1]), fmaxf(sv[1][2], sv[1][3])));
            m0 = fmaxf(m0, fmaxf(fmaxf(sv[2][0], sv[2][1]), fmaxf(sv[2][2], sv[2][3])));
            m0 = fmaxf(m0, fmaxf(fmaxf(sv[3][0], sv[3][1]), fmaxf(sv[3][2], sv[3][3])));
            m0 = fmaxf(m0, __shfl_xor(m0, 16));
            m0 = fmaxf(m0, __shfl_xor(m0, 32));

            if (__any(m0 > m_run + 90.5f)) {
                float mn = fmaxf(m_run, m0);
                float al = exp2f((m_run - mn) * C2);
                m_run = mn;
                l_run *= al;
                #pragma unroll
                for (int db = 0; db < 8; ++db)
                    #pragma unroll
                    for (int r = 0; r < 4; ++r)
                        o_acc[db][r] *= al;
            }

            unsigned pk[4][2];
            float mb2 = m_run * C2;
            float rs = 0.f;
            #pragma unroll
            for (int kvb = 0; kvb < 4; ++kvb) {
                float p0 = exp2f(fmaf(sv[kvb][0], C2, -mb2));
                float p1 = exp2f(fmaf(sv[kvb][1], C2, -mb2));
                float p2 = exp2f(fmaf(sv[kvb][2], C2, -mb2));
                float p3 = exp2f(fmaf(sv[kvb][3], C2, -mb2));
                rs += (p0 + p1) + (p2 + p3);
                pk[kvb][0] = (unsigned)f2bf(p0) | ((unsigned)f2bf(p1) << 16);
                pk[kvb][1] = (unsigned)f2bf(p2) | ((unsigned)f2bf(p3) << 16);
            }
            rs += __shfl_xor(rs, 16);
            rs += __shfl_xor(rs, 32);
            l_run += rs;

            #pragma unroll
            for (int kk = 0; kk < 2; ++kk) {
                u32x4 w;
                unsigned a0 = (unsigned)__shfl((int)pk[2 * kk][0], srcb);
                unsigned a1 = (unsigned)__shfl((int)pk[2 * kk][1], srcb);
                unsigned a2 = (unsigned)__shfl((int)pk[2 * kk][0], srcb + 16);
                unsigned a3 = (unsigned)__shfl((int)pk[2 * kk][1], srcb + 16);
                unsigned b0 = (unsigned)__shfl((int)pk[2 * kk + 1][0], srcb);
                unsigned b1 = (unsigned)__shfl((int)pk[2 * kk + 1][1], srcb);
                unsigned b2 = (unsigned)__shfl((int)pk[2 * kk + 1][0], srcb + 16);
                unsigned b3 = (unsigned)__shfl((int)pk[2 * kk + 1][1], srcb + 16);
                w[0] = hig ? b0 : a0;
                w[1] = hig ? b1 : a1;
                w[2] = hig ? b2 : a2;
                w[3] = hig ? b3 : a3;
                bf16x8 pb = *reinterpret_cast<const bf16x8*>(&w);
                __builtin_amdgcn_s_setprio(1);
                #pragma unroll
                for (int db = 0; db < 8; ++db) {
                    bf16x8 vf = *reinterpret_cast<const bf16x8*>(
                        &Vs[(db * 16 + lr) * 64 + (((kk * 4 + g) ^ (lr & 7)) * 8)]);
                    o_acc[db] = __builtin_amdgcn_mfma_f32_16x16x32_bf16(
                        vf, pb, o_acc[db], 0, 0, 0);
                }
                __builtin_amdgcn_s_setprio(0);
            }
        }
    }

    {
        float inv = 1.f / l_run;
        size_t rowb = ((size_t)(b * S_ + q0w + lr) * NH_ + h) * HD_;
        #pragma unroll
        for (int db = 0; db < 8; ++db) {
            ushort4 o4;
            o4.x = f2bf(o_acc[db][0] * inv);
            o4.y = f2bf(o_acc[db][1] * inv);
            o4.z = f2bf(o_acc[db][2] * inv);
            o4.w = f2bf(o_acc[db][3] * inv);
            *reinterpret_cast<ushort4*>(&O[rowb + db * 16 + g * 4]) = o4;
        }
    }
}

// ---------------- launcher ----------------
extern "C" void kernel_launch(void* const* d_in, const int* in_sizes, int n_in,
                              void* d_out, int out_size, void* d_ws, size_t ws_size,
                              hipStream_t stream)
{
    const float* x  = (const float*)d_in[0];
    const float* wq = (const float*)d_in[1];
    const float* wk = (const float*)d_in[2];
    const float* wv = (const float*)d_in[3];
    const float* wo = (const float*)d_in[4];
    float* out = (float*)d_out;

    char* ws = (char*)d_ws;
    size_t off = 0;
    auto alloc = [&](size_t bytes) -> void* {
        void* p = ws + off;
        off += (bytes + 255) & ~(size_t)255;
        return p;
    };
    unsigned short* xb   = (unsigned short*)alloc((size_t)B_ * S_ * DIM_ * 2);
    unsigned short* wqkb = (unsigned short*)alloc((size_t)3072 * 2048 * 2);
    unsigned short* wvb  = (unsigned short*)alloc((size_t)1024 * 2048 * 2);
    unsigned short* wob  = (unsigned short*)alloc((size_t)DIM_ * DIM_ * 2);
    unsigned short* QKb  = (unsigned short*)alloc((size_t)B_ * S_ * 3072 * 2);
    unsigned short* Vtb  = (unsigned short*)alloc((size_t)1024 * B_ * S_ * 2);
    unsigned short* Ob   = (unsigned short*)alloc((size_t)B_ * S_ * NH_ * HD_ * 2);
    float* tab = (float*)alloc((size_t)S_ * 64 * 2 * 4);

    k_convert<<<20992, 256, 0, stream>>>(x, wq, wk, wv, wo, xb, wqkb, wvb, wob, tab);
    k_gemm_qkv<<<256, 512, 0, stream>>>(xb, wqkb, wvb, QKb, Vtb, tab);
    k_attn<<<B_ * NH_ * (S_ / 128), 512, 0, stream>>>(QKb, Vtb, Ob);
    k_gemm_op<<<256, 512, 0, stream>>>(Ob, wob, out);

    (void)in_sizes; (void)n_in; (void)out_size; (void)ws_size;
}